// Round 7
// baseline (298.453 us; speedup 1.0000x reference)
//
#include <hip/hip_runtime.h>
#include <hip/hip_bf16.h>

#define HW 65536
#define CCH 128

typedef __attribute__((ext_vector_type(8))) short short8;
typedef __attribute__((ext_vector_type(4))) float f32x4;
typedef __attribute__((ext_vector_type(8))) unsigned short u16x8;

__device__ __forceinline__ void gload_lds16(const void* g, void* l) {
    __builtin_amdgcn_global_load_lds((const __attribute__((address_space(1))) void*)g,
                                     (__attribute__((address_space(3))) void*)l, 16, 0, 0);
}
__device__ __forceinline__ unsigned short f2bf(float f) {
    union { float f; unsigned int i; } u; u.f = f;
    unsigned int r = u.i + 0x7fffu + ((u.i >> 16) & 1u);
    return (unsigned short)(r >> 16);
}
__device__ __forceinline__ float bf2f(unsigned short h) {
    union { unsigned int i; float f; } u; u.i = ((unsigned int)h) << 16; return u.f;
}
__device__ __forceinline__ unsigned int cvt_pk_bf16(float lo, float hi) {
    unsigned int r;
    asm("v_cvt_pk_bf16_f32 %0, %1, %2" : "=v"(r) : "v"(lo), "v"(hi));
    return r;
}

// ---------------- K1: adaptive avg pool 256x256 -> 8x8, f32x4 lanes ----------------
__global__ __launch_bounds__(256) void pool_kernel(const float* __restrict__ x,
                                                   float* __restrict__ pooled) {
    int bc = blockIdx.x;
    const float* base = x + (size_t)bc * HW;
    int t = threadIdx.x;
    int w = t >> 6, l = t & 63;
    for (int it = 0; it < 2; ++it) {
        int py = w + it * 4;
        const float* rp = base + py * 32 * 256 + l * 4;
        f32x4 s0 = {0.f, 0.f, 0.f, 0.f};
        f32x4 s1 = {0.f, 0.f, 0.f, 0.f};
        #pragma unroll
        for (int r = 0; r < 32; r += 2) {
            s0 += *(const f32x4*)(rp + r * 256);
            s1 += *(const f32x4*)(rp + (r + 1) * 256);
        }
        f32x4 sv = s0 + s1;
        float acc = sv[0] + sv[1] + sv[2] + sv[3];
        acc += __shfl_down(acc, 4, 8);
        acc += __shfl_down(acc, 2, 8);
        acc += __shfl_down(acc, 1, 8);
        if ((l & 7) == 0)
            pooled[(size_t)bc * 64 + py * 8 + (l >> 3)] = acc * (1.0f / 1024.0f);
    }
}

// ---------------- K2: fused prep via S = k^T Wv factorization (all fp32) ----------------
// per bh block: q,k = relu(pooled@W^T+b); S[p][e] = sum_d k[d][p] Wv[d][e];
// t[p] = sum_d k[d][p]; u[p] = sum_d k[d][p] bv[d];
// M[c][e] = (q[c]·S[:,e]) / (q[c]·t + eps); beta[c] = (q[c]·u) / (q[c]·t + eps)
__global__ __launch_bounds__(256) void prep_kernel(
        const float* __restrict__ pooled,
        const float* __restrict__ Wq, const float* __restrict__ bq,
        const float* __restrict__ Wk, const float* __restrict__ bk,
        const float* __restrict__ Wv, const float* __restrict__ bv,
        unsigned short* __restrict__ Mo, float* __restrict__ beta) {
    int bh = blockIdx.x;
    int b = bh >> 3, h = bh & 7;
    int t = threadIdx.x;
    __shared__ __align__(16) char sm[137216];
    float* S   = (float*)sm;             // [64][132] (phase 2+)   33792 B
    float* Wvs = (float*)(sm + 33792);   // [64][128] staged half  32768 B
    float* ps  = (float*)sm;             // phase 0/1 [128][64]    32768 B (overlay)
    float* Wqs = (float*)(sm + 32768);   // [64][64] (overlay)
    float* Wks = (float*)(sm + 49152);   // [64][64] (overlay)
    float* qs  = (float*)(sm + 66560);   // [128][68]
    float* ks  = (float*)(sm + 101376);  // [128][68]
    float* bvs = (float*)(sm + 136192);  // [128]
    float* tv  = (float*)(sm + 136704);  // [64]
    float* uv  = (float*)(sm + 136960);  // [64]

    // ---- phase 0: stage pooled[b], Wq/Wk head rows, bv ----
    for (int i = t; i < 2048; i += 256) {
        int c = i >> 4, p4 = (i & 15) * 4;
        *(f32x4*)&ps[c * 64 + p4] = *(const f32x4*)(pooled + (size_t)(b * CCH + c) * 64 + p4);
    }
    for (int i = t; i < 1024; i += 256) {
        int r = i >> 4, p4 = (i & 15) * 4;
        *(f32x4*)&Wqs[r * 64 + p4] = *(const f32x4*)(Wq + (size_t)(h * 64 + r) * 64 + p4);
        *(f32x4*)&Wks[r * 64 + p4] = *(const f32x4*)(Wk + (size_t)(h * 64 + r) * 64 + p4);
    }
    if (t < 128) bvs[t] = bv[t];
    __syncthreads();

    // ---- phase 1: q,k = relu(ps @ W^T + b), all 128 rows each ----
    {
        int p = t & 63, g = t >> 6;
        f32x4 wr[16];
        #pragma unroll
        for (int j = 0; j < 16; ++j) wr[j] = *(const f32x4*)&Wks[p * 64 + j * 4];
        float bkv = bk[h * 64 + p];
        for (int dd = 0; dd < 32; ++dd) {
            int d = g * 32 + dd;
            float acc = bkv;
            #pragma unroll
            for (int j = 0; j < 16; ++j) {
                f32x4 pv = *(const f32x4*)&ps[d * 64 + j * 4];
                acc += pv[0] * wr[j][0] + pv[1] * wr[j][1] + pv[2] * wr[j][2] + pv[3] * wr[j][3];
            }
            ks[d * 68 + p] = fmaxf(acc, 0.f);
        }
        #pragma unroll
        for (int j = 0; j < 16; ++j) wr[j] = *(const f32x4*)&Wqs[p * 64 + j * 4];
        float bqv = bq[h * 64 + p];
        for (int dd = 0; dd < 32; ++dd) {
            int c = g * 32 + dd;
            float acc = bqv;
            #pragma unroll
            for (int j = 0; j < 16; ++j) {
                f32x4 pv = *(const f32x4*)&ps[c * 64 + j * 4];
                acc += pv[0] * wr[j][0] + pv[1] * wr[j][1] + pv[2] * wr[j][2] + pv[3] * wr[j][3];
            }
            qs[c * 68 + p] = fmaxf(acc, 0.f);
        }
    }
    __syncthreads();   // phase 1 done; ps/Wqs/Wks dead

    // ---- phase 2: S = k^T Wv (d in two staged halves), t, u ----
    {
        int p = t >> 2, ec = t & 3;
        float acc[32] = {};
        float tacc = 0.f, uacc = 0.f;
        for (int half = 0; half < 2; ++half) {
            for (int i = t; i < 2048; i += 256) {
                int dl = i >> 5, e4 = (i & 31) * 4;
                *(f32x4*)&Wvs[dl * 128 + e4] =
                    *(const f32x4*)(Wv + (size_t)(half * 64 + dl) * 128 + e4);
            }
            __syncthreads();
            for (int dd = 0; dd < 64; ++dd) {
                int d = half * 64 + dd;
                float kv = ks[d * 68 + p];
                tacc += kv;
                uacc += kv * bvs[d];
                #pragma unroll
                for (int j = 0; j < 8; ++j) {
                    f32x4 wv4 = *(const f32x4*)&Wvs[dd * 128 + ec * 4 + j * 16];
                    acc[j * 4 + 0] += kv * wv4[0];
                    acc[j * 4 + 1] += kv * wv4[1];
                    acc[j * 4 + 2] += kv * wv4[2];
                    acc[j * 4 + 3] += kv * wv4[3];
                }
            }
            __syncthreads();   // done reading this Wvs half
        }
        #pragma unroll
        for (int j = 0; j < 8; ++j) {
            f32x4 v = {acc[j * 4], acc[j * 4 + 1], acc[j * 4 + 2], acc[j * 4 + 3]};
            *(f32x4*)&S[p * 132 + ec * 4 + j * 16] = v;
        }
        if (ec == 0) { tv[p] = tacc; uv[p] = uacc; }
    }
    __syncthreads();

    // ---- phase 3: M[c][e] = (q[c]·S[:,e]) * inv_c ; beta ----
    {
        int c = t >> 1, eh = t & 1;
        f32x4 qr[16];
        #pragma unroll
        for (int j = 0; j < 16; ++j) qr[j] = *(const f32x4*)&qs[c * 68 + j * 4];
        float den = 0.f, bacc = 0.f;
        #pragma unroll
        for (int p = 0; p < 64; ++p) {
            float qv = qr[p >> 2][p & 3];
            den += qv * tv[p];
            bacc += qv * uv[p];
        }
        float inv = 1.0f / (den + 1e-7f);
        if (eh == 0) beta[bh * 128 + c] = bacc * inv;
        unsigned short* Mb = Mo + (size_t)bh * 16384 + c * 128 + eh * 64;
        #pragma unroll
        for (int chunk = 0; chunk < 2; ++chunk) {
            float acc[32] = {};
            int ebase = eh * 64 + chunk * 32;
            #pragma unroll
            for (int p = 0; p < 64; ++p) {
                float qv = qr[p >> 2][p & 3];
                #pragma unroll
                for (int j = 0; j < 8; ++j) {
                    f32x4 sv = *(const f32x4*)&S[p * 132 + ebase + j * 4];
                    acc[j * 4 + 0] += qv * sv[0];
                    acc[j * 4 + 1] += qv * sv[1];
                    acc[j * 4 + 2] += qv * sv[2];
                    acc[j * 4 + 3] += qv * sv[3];
                }
            }
            union { unsigned int u[16]; uint4 v4[4]; } pk;
            #pragma unroll
            for (int j = 0; j < 16; ++j)
                pk.u[j] = cvt_pk_bf16(acc[2 * j] * inv, acc[2 * j + 1] * inv);
            #pragma unroll
            for (int j = 0; j < 4; ++j)
                *(uint4*)(Mb + chunk * 32 + j * 8) = pk.v4[j];
        }
    }
}

// ---------------- K3: attn[c][s] = sum_e M[c][e]*x[e][s] + beta[c], bf16 MFMA ----------------
__global__ __launch_bounds__(512, 4) void attn_kernel(
        const float* __restrict__ x,
        const __hip_bfloat16* __restrict__ Mbf,
        const float* __restrict__ beta,
        __hip_bfloat16* __restrict__ attn) {
    int bid = blockIdx.x;
    int bh = bid >> 4;
    int chunk = bid & 15;
    int b = bh >> 3, h = bh & 7;
    int s0g = h * 8192 + chunk * 512;
    int tid = threadIdx.x;
    int w = tid >> 6, l = tid & 63;

    __shared__ __align__(16) char sm[65536];  // M@0 (32K), ts dbuf @32768 (2x16K)
    char* ts0 = sm + 32768;

    const char* Mg = (const char*)(Mbf + (size_t)bh * 16384);
    #pragma unroll
    for (int i = 0; i < 4; ++i) {
        int o = i * 8192 + tid * 16;
        int osw = o ^ (((o >> 8) & 7) << 4);
        gload_lds16(Mg + osw, sm + o);
    }

    int e0u = (tid >> 4) * 2;
    int s4u = (tid & 15) * 4;
    const float* xb = x + (size_t)b * CCH * HW + s0g;

    f32x4 rg[4];
    #define LOADT(t_) do { \
        const float* p0 = xb + (size_t)e0u * HW + (t_) * 64 + s4u; \
        rg[0] = *(const f32x4*)p0; \
        rg[1] = *(const f32x4*)(p0 + HW); \
        const float* p1 = p0 + (size_t)64 * HW; \
        rg[2] = *(const f32x4*)p1; \
        rg[3] = *(const f32x4*)(p1 + HW); \
    } while (0)
    #define WRITET(buf_) do { \
        _Pragma("unroll") \
        for (int j = 0; j < 4; ++j) { \
            int s = s4u + j; \
            int sw = (s & 7) << 4; \
            unsigned int pa = cvt_pk_bf16(rg[0][j], rg[1][j]); \
            unsigned int pb = cvt_pk_bf16(rg[2][j], rg[3][j]); \
            *(unsigned int*)((buf_) + ((s * 256 + e0u * 2) ^ sw)) = pa; \
            *(unsigned int*)((buf_) + ((s * 256 + (e0u + 64) * 2) ^ sw)) = pb; \
        } \
    } while (0)

    LOADT(0);
    WRITET(ts0);
    LOADT(1);
    __syncthreads();

    int c0w = (w >> 1) * 32;
    int s0w = (w & 1) * 32;
    short8 mf[2][4];
    #pragma unroll
    for (int ci = 0; ci < 2; ++ci)
        #pragma unroll
        for (int ksi = 0; ksi < 4; ++ksi) {
            int c = c0w + ci * 16 + (l & 15);
            int o = (c * 256 + ksi * 64 + ((l >> 4) * 16)) ^ ((c & 7) << 4);
            mf[ci][ksi] = *(const short8*)(sm + o);
        }
    const float* bet = beta + bh * 128;
    float bv0 = bet[c0w + (l & 15)];
    float bv1 = bet[c0w + 16 + (l & 15)];
    __hip_bfloat16* ab = attn + (size_t)b * CCH * HW + s0g;

    for (int t = 0; t < 8; ++t) {
        char* tsc = ts0 + (t & 1) * 16384;
        if (t < 7) WRITET(ts0 + ((t + 1) & 1) * 16384);
        if (t < 6) LOADT(t + 2);
        f32x4 acc[2][2] = {};
        #pragma unroll
        for (int ksi = 0; ksi < 4; ++ksi) {
            short8 af[2];
            #pragma unroll
            for (int si = 0; si < 2; ++si) {
                int s = s0w + si * 16 + (l & 15);
                int o = (s * 256 + ksi * 64 + ((l >> 4) * 16)) ^ ((s & 7) << 4);
                af[si] = *(const short8*)(tsc + o);
            }
            #pragma unroll
            for (int si = 0; si < 2; ++si)
                #pragma unroll
                for (int ci = 0; ci < 2; ++ci)
                    acc[si][ci] = __builtin_amdgcn_mfma_f32_16x16x32_bf16(af[si], mf[ci][ksi], acc[si][ci], 0, 0, 0);
        }
        #pragma unroll
        for (int si = 0; si < 2; ++si)
            #pragma unroll
            for (int ci = 0; ci < 2; ++ci) {
                int sb = s0w + si * 16 + (l >> 4) * 4;
                int c = c0w + ci * 16 + (l & 15);
                float bvv = ci ? bv1 : bv0;
                uint2 pk2;
                pk2.x = cvt_pk_bf16(acc[si][ci][0] + bvv, acc[si][ci][1] + bvv);
                pk2.y = cvt_pk_bf16(acc[si][ci][2] + bvv, acc[si][ci][3] + bvv);
                *(uint2*)(ab + (size_t)c * HW + t * 64 + sb) = pk2;
            }
        __syncthreads();
    }
    #undef LOADT
    #undef WRITET
}

// ---------------- K4: depthwise 3x3 pad1 + bp, registers + shfl halos, no LDS ----------------
__global__ __launch_bounds__(256) void dwconv_kernel(const __hip_bfloat16* __restrict__ attn,
        const float* __restrict__ Wp, const float* __restrict__ bp,
        float* __restrict__ out) {
    int bid = blockIdx.x;
    int bc = bid >> 5;
    int y0 = (bid & 31) * 8;
    int t = threadIdx.x;
    int l = t & 63;
    int y = y0 + ((t >> 6) << 1) + (l >> 5);   // wave = 2 full image rows
    int xl = l & 31;
    int xc = xl * 8;
    const unsigned short* base = (const unsigned short*)attn + (size_t)bc * HW;
    int c = bc & 127;
    float wv[9];
    #pragma unroll
    for (int j = 0; j < 9; ++j) wv[j] = Wp[c * 9 + j];
    float bias = bp[c];
    float accv[8];
    #pragma unroll
    for (int j = 0; j < 8; ++j) accv[j] = bias;
    #pragma unroll
    for (int dy = 0; dy < 3; ++dy) {
        int gy = y + dy - 1;
        u16x8 m = (u16x8)((unsigned short)0);
        if (gy >= 0 && gy < 256) m = *(const u16x8*)(base + gy * 256 + xc);
        float f[8];
        #pragma unroll
        for (int j = 0; j < 8; ++j) f[j] = bf2f(m[j]);
        float lf = __shfl(f[7], l - 1);
        float rf = __shfl(f[0], l + 1);
        if (xl == 0) lf = 0.f;
        if (xl == 31) rf = 0.f;
        float w0 = wv[dy * 3], w1 = wv[dy * 3 + 1], w2 = wv[dy * 3 + 2];
        accv[0] += w0 * lf + w1 * f[0] + w2 * f[1];
        #pragma unroll
        for (int j = 1; j < 7; ++j)
            accv[j] += w0 * f[j - 1] + w1 * f[j] + w2 * f[j + 1];
        accv[7] += w0 * f[6] + w1 * f[7] + w2 * rf;
    }
    float* op = out + (size_t)bc * HW + (size_t)y * 256 + xc;
    float4 o0 = {accv[0], accv[1], accv[2], accv[3]};
    float4 o1 = {accv[4], accv[5], accv[6], accv[7]};
    *(float4*)op = o0;
    *(float4*)(op + 4) = o1;
}

extern "C" void kernel_launch(void* const* d_in, const int* in_sizes, int n_in,
                              void* d_out, int out_size, void* d_ws, size_t ws_size,
                              hipStream_t stream) {
    const float* x  = (const float*)d_in[0];
    const float* Wq = (const float*)d_in[1];
    const float* bq = (const float*)d_in[2];
    const float* Wk = (const float*)d_in[3];
    const float* bk = (const float*)d_in[4];
    const float* Wv = (const float*)d_in[5];
    const float* bv = (const float*)d_in[6];
    const float* Wp = (const float*)d_in[7];
    const float* bp = (const float*)d_in[8];
    float* out = (float*)d_out;
    char* ws = (char*)d_ws;

    float* pooled      = (float*)ws;                            // 256 KB
    unsigned short* Mo = (unsigned short*)(ws + 262144);        // 2 MB
    float* betab       = (float*)(ws + 2359296);                // 32 KB
    char* attnp        = ws + 2392064;                          // 128 MB

    pool_kernel<<<dim3(1024), dim3(256), 0, stream>>>(x, pooled);
    prep_kernel<<<dim3(64), dim3(256), 0, stream>>>(pooled, Wq, bq, Wk, bk, Wv, bv, Mo, betab);
    attn_kernel<<<dim3(1024), dim3(512), 0, stream>>>(x, (const __hip_bfloat16*)Mo, betab, (__hip_bfloat16*)attnp);
    dwconv_kernel<<<dim3(32768), dim3(256), 0, stream>>>((const __hip_bfloat16*)attnp, Wp, bp, out);
}